// Round 10
// baseline (352.441 us; speedup 1.0000x reference)
//
#include <hip/hip_runtime.h>
#include <hip/hip_bf16.h>

// TaylorMap, symmetric-packed quadratic, uniform-9 pair stream.
// R10: f16 + scale-folded-into-B => MFMA accumulates DIRECTLY into acc.
// x_{t+1} = x_t + W0 + W1^T x + sum_{i<=j} x_i x_j (W2fold[i,j,:]), 7 steps.
// R9 post-mortem: 47% MfmaUtil; stall = serial 8-MFMA Y-chains + 64 chain-end
// v_fmacs per pair. Fix: the per-pair scale x_p is a per-batch-column scalar,
// and the B-operand lane owns one column -> fold the scale into B with
// v_pk_mul_f16 (4/slice) and accumulate straight into acc via the MFMA
// C-operand. No Y/Z transients (frees 64 AGPRs), no fmacs, 4 long acc chains
// per SIMD. bf16 -> f16 because v_pk_mul_bf16 doesn't exist; numerics: A is
// pre-scaled x256 in prep (folded W ~ 2.6e-2, normal f16 range) and 1/256 is
// folded into the per-pair scale, so no f16 denormal exposure; f16 beats bf16
// precision here. Register shape: abuf[9] rotating (36) + bfrag0/1 (64) +
// addr/scales ~24 = ~124 arch <= 128 (R9-proven), acc = 32 AGPR.
// LDS kept 84.5 KB -> 1 block/CU -> 2 waves/SIMD reg target (R3 trap off).

#define DSTATE 128
#define BATCH  16384
#define NSTEPS 7
#define BT     64
#define NSL    585          // slices per d-tile: 64*9 pair + 8 linear + 1 pad
#define ASCALE 256.0f
#define INVAS  0.00390625f  // 1/256, exact

typedef __attribute__((ext_vector_type(8)))  _Float16 half8;  // 8 f16 = 4 VGPRs
typedef __attribute__((ext_vector_type(16))) float    f32x16; // MFMA 32x32 C/D

__device__ __forceinline__ half8 splat8(_Float16 h){
    half8 v = {h, h, h, h, h, h, h, h};
    return v;
}

// Pack symmetric-folded W into f16 MFMA-A fragments (x256), uniform-9 pairs.
// Pair p at positions 9p..9p+8: first 8-(p>>4) slices are row p (j-blocks
// p>>4..7), remaining 1+(p>>4) are row 127-p (j-blocks 7-(p>>4)..7).
// Fragment layout: A[m][k], m=lane&31 -> d=32t+m, k=(lane>>5)*8+e -> j=16*s+k.
__global__ void prep_kernel(const float* __restrict__ W, half8* __restrict__ A){
    int gid = blockIdx.x * 256 + threadIdx.x;
    const int ntotal = 4 * 130 * 8 * 64;
    if (gid >= ntotal) return;
    int lane = gid & 63; int r = gid >> 6;
    int s = r & 7;  r >>= 3;
    int row = r % 130;
    int t   = r / 130;
    int d  = t * 32 + (lane & 31);
    int kb = (lane >> 5) * 8;
    int dst;
    bool zero = false;
    if (row < 64){
        int sl = row >> 4;
        if (s < sl) return;
        dst = t * NSL + 9 * row + (s - sl);
    } else if (row < 128){
        int p  = 127 - row;
        int sl = row >> 4;
        if (s < sl) return;
        int ca = 8 - (p >> 4);
        dst = t * NSL + 9 * p + ca + (s - sl);
    } else if (row == 128){
        dst = t * NSL + 576 + s;               // linear (W1) row
    } else {
        if (s) return;                         // zero pad slice
        dst = t * NSL + 584;
        zero = true;
    }
    union { half8 v; _Float16 u[8]; } fr;
#pragma unroll
    for (int e = 0; e < 8; ++e){
        int j = s * 16 + kb + e;
        float v;
        if (zero) v = 0.0f;
        else if (row < 128){
            if      (j < row)  v = 0.0f;
            else if (j == row) v = W[(129 + 128 * row + j) * 128 + d];
            else               v = W[(129 + 128 * row + j) * 128 + d]
                                 + W[(129 + 128 * j + row) * 128 + d];
        } else {
            v = W[(1 + j) * 128 + d];
        }
        fr.u[e] = (_Float16)(v * ASCALE);
    }
    A[(size_t)dst * 64 + lane] = fr.v;
}

__global__ __launch_bounds__(512)
void taylor_kernel(const float* __restrict__ X, const float* __restrict__ W,
                   const float* __restrict__ tini, const float* __restrict__ lini,
                   const half8* __restrict__ A, float* __restrict__ out)
{
    __shared__ float  x_lds[DSTATE * BT];      // fp32 master state [d][b], 32 KB
    __shared__ float  w0_lds[DSTATE];
    __shared__ half8  bpack[2 * 8 * 64];       // B frags, 2 groups x 8 slices, 16 KB
    __shared__ float  sc_lds[2][4 * 64 * 17];  // K-merge scratch, 34.8 KB

    const int tid  = threadIdx.x;
    const int lane = tid & 63;
    const int w    = tid >> 6;
    const int t    = w & 3;                    // d-tile
    const int g    = w >> 2;                   // K-half (pairs 0..31 / 32..63+lin)
    const int ln   = lane & 31;
    const int hi   = lane >> 5;
    const int b0   = blockIdx.x * BT;

    // ---- init x0 = [X | t_init | l_init] ----
#pragma unroll
    for (int it = 0; it < 16; ++it){
        int entry = tid + it * 512;            // entry = b*128 + d
        int b = entry >> 7, d = entry & 127;
        float v;
        if      (d < 120) v = X[(b0 + b) * 120 + d];
        else if (d < 124) v = tini[d - 120];
        else              v = lini[d - 124];
        x_lds[d * BT + b] = v;
    }
    if (tid < DSTATE) w0_lds[tid] = W[tid];

    // wave's half-stream base: g0 -> slice 0, g1 -> slice 288 (pair 32)
    const half8* const Aw = A + ((size_t)t * NSL + (size_t)g * 288) * 64 + lane;

#pragma unroll 1
    for (int step = 0; step < NSTEPS; ++step){
        __syncthreads();                       // (A) x_lds stable

        // ---- prime A stream: first pair of this wave's half ----
        const half8* ap = Aw;
        half8 abuf[9];
#pragma unroll
        for (int s = 0; s < 9; ++s) abuf[s] = ap[s * 64];
        ap += 9 * 64;                          // reloads during pair q read q+1

        // ---- build bpack (1024 frags, 2 per thread) while loads fly ----
#pragma unroll
        for (int f0 = 0; f0 < 2; ++f0){
            int f  = tid + f0 * 512;
            int gg = f >> 9, s = (f >> 6) & 7, l = f & 63;
            int c  = gg * 32 + (l & 31);
            int jb = 16 * s + 8 * (l >> 5);
            union { half8 v; _Float16 u[8]; } fr;
#pragma unroll
            for (int e = 0; e < 8; ++e)
                fr.u[e] = (_Float16)x_lds[(jb + e) * BT + c];
            bpack[f] = fr.v;
        }

        // ---- acc: g0 carries x_old + W0 for both groups; g1 pure partial ----
        f32x16 acc0, acc1;
        if (g == 0){
#pragma unroll
            for (int r = 0; r < 16; ++r){
                int d = 32 * t + (r & 3) + 8 * (r >> 2) + 4 * hi;
                acc0[r] = x_lds[d * BT + ln]      + w0_lds[d];
                acc1[r] = x_lds[d * BT + 32 + ln] + w0_lds[d];
            }
        } else {
#pragma unroll
            for (int r = 0; r < 16; ++r){ acc0[r] = 0.f; acc1[r] = 0.f; }
        }

        __syncthreads();                       // (B) bpack visible

        half8 bfrag0[8], bfrag1[8];            // B reg-cache for current BK block

        // pair p=16*BK+q: rows (p,127-p). Y: slices BK..7 (abuf[0..7-BK]),
        // Z: slices 7-BK..7 (abuf[8-BK..8], bfrag idx 7-2BK+s). Scale folded
        // into B per pair (v_pk_mul_f16), MFMA accumulates directly into acc.
        // abuf[s] reloaded for the NEXT pair right after its 2 consumers issue.
#define PAIRS(BK)                                                               \
        {                                                                       \
            _Pragma("unroll")                                                   \
            for (int s = 0; s < 8 - (BK); ++s){                                 \
                bfrag0[s] = bpack[((BK) + s) * 64 + lane];                      \
                bfrag1[s] = bpack[512 + ((BK) + s) * 64 + lane];                \
            }                                                                   \
            _Pragma("unroll 2")                                                 \
            for (int q = 0; q < 16; ++q){                                       \
                const int p = 16 * (BK) + q;                                    \
                half8 v0a = splat8((_Float16)(x_lds[p * BT + ln]            * INVAS)); \
                half8 v0b = splat8((_Float16)(x_lds[p * BT + 32 + ln]       * INVAS)); \
                half8 v1a = splat8((_Float16)(x_lds[(127 - p) * BT + ln]      * INVAS)); \
                half8 v1b = splat8((_Float16)(x_lds[(127 - p) * BT + 32 + ln] * INVAS)); \
                _Pragma("unroll")                                               \
                for (int s = 0; s < 8 - (BK); ++s){                             \
                    acc0 = __builtin_amdgcn_mfma_f32_32x32x16_f16(abuf[s], v0a * bfrag0[s], acc0, 0, 0, 0); \
                    acc1 = __builtin_amdgcn_mfma_f32_32x32x16_f16(abuf[s], v0b * bfrag1[s], acc1, 0, 0, 0); \
                    abuf[s] = ap[s * 64];                                       \
                }                                                               \
                _Pragma("unroll")                                               \
                for (int s = 0; s < 1 + (BK); ++s){                             \
                    acc0 = __builtin_amdgcn_mfma_f32_32x32x16_f16(abuf[8 - (BK) + s], v1a * bfrag0[7 - 2 * (BK) + s], acc0, 0, 0, 0); \
                    acc1 = __builtin_amdgcn_mfma_f32_32x32x16_f16(abuf[8 - (BK) + s], v1b * bfrag1[7 - 2 * (BK) + s], acc1, 0, 0, 0); \
                    abuf[8 - (BK) + s] = ap[(8 - (BK) + s) * 64];               \
                }                                                               \
                ap += 9 * 64;                                                   \
            }                                                                   \
        }

        if (g == 0){
            PAIRS(0) PAIRS(1)
            // q=15 reloads read pair 32 (in-bounds, discarded)
        } else {
            PAIRS(2) PAIRS(3)
            // q=15 reloads of PAIRS(3) left abuf[0..7] = linear (W1) row x256,
            // abuf[8] = pad. Linear scale = 1 -> folded 1/256 (exact pow2).
            const half8 vlin = splat8((_Float16)INVAS);
#pragma unroll
            for (int s = 0; s < 8; ++s){
                bfrag0[s] = bpack[s * 64 + lane];
                bfrag1[s] = bpack[512 + s * 64 + lane];
            }
#pragma unroll
            for (int s = 0; s < 8; ++s){
                acc0 = __builtin_amdgcn_mfma_f32_32x32x16_f16(abuf[s], vlin * bfrag0[s], acc0, 0, 0, 0);
                acc1 = __builtin_amdgcn_mfma_f32_32x32x16_f16(abuf[s], vlin * bfrag1[s], acc1, 0, 0, 0);
            }
            // publish K-half partials
#pragma unroll
            for (int r = 0; r < 16; ++r){
                sc_lds[0][(t * 64 + lane) * 17 + r] = acc0[r];
                sc_lds[1][(t * 64 + lane) * 17 + r] = acc1[r];
            }
        }
#undef PAIRS

        __syncthreads();                       // (C) reads done + scratch visible
        if (g == 0){
#pragma unroll
            for (int r = 0; r < 16; ++r){
                acc0[r] += sc_lds[0][(t * 64 + lane) * 17 + r];
                acc1[r] += sc_lds[1][(t * 64 + lane) * 17 + r];
            }
            if (step < NSTEPS - 1){
#pragma unroll
                for (int r = 0; r < 16; ++r){
                    int d = 32 * t + (r & 3) + 8 * (r >> 2) + 4 * hi;
                    x_lds[d * BT + ln]      = acc0[r];
                    x_lds[d * BT + 32 + ln] = acc1[r];
                }
            } else if (t == 3 && hi == 0){
                // out dims 120..123 -> tile 3, regs 12..15 @ hi==0
                *(float4*)(out + (size_t)(b0 + ln) * 4) =
                    make_float4(acc0[12], acc0[13], acc0[14], acc0[15]);
                *(float4*)(out + (size_t)(b0 + 32 + ln) * 4) =
                    make_float4(acc1[12], acc1[13], acc1[14], acc1[15]);
            }
        }
        // next iteration's barrier (A) orders g0's x write vs g1's next reads
    }
}

extern "C" void kernel_launch(void* const* d_in, const int* in_sizes, int n_in,
                              void* d_out, int out_size, void* d_ws, size_t ws_size,
                              hipStream_t stream)
{
    const float* X  = (const float*)d_in[0];
    const float* W  = (const float*)d_in[1];
    const float* ti = (const float*)d_in[2];
    const float* li = (const float*)d_in[3];
    float* out      = (float*)d_out;
    half8* A        = (half8*)d_ws;            // 4*585*64*16 B = 2.40 MB

    const int ntotal = 4 * 130 * 8 * 64;
    prep_kernel<<<(ntotal + 255) / 256, 256, 0, stream>>>(W, A);
    taylor_kernel<<<BATCH / BT, 512, 0, stream>>>(X, W, ti, li, A, out);
}

// Round 11
// 332.811 us; speedup vs baseline: 1.0590x; 1.0590x over previous
//
#include <hip/hip_runtime.h>
#include <hip/hip_bf16.h>

// TaylorMap, symmetric-packed quadratic, uniform-9 pair stream (bf16, R9 base).
// R11 = R9 + (1) one-pair-deep DEFERRED Y-fmacs: per pair do prev-pair's Y
// fmacs first (Y complete -> zero stall), then Z chains, Y chains (into
// carried Yp), Z fmacs (covered by Y-issue span). No chain-end MFMA-latency
// stall remains. (2) last-step pruning: step 7 only needs d-tile 3 -> t!=3
// waves skip compute (barriers uniform). (3) linear row accumulates directly
// into acc via MFMA C-operand (scale==1, no fmac).
// R10 post-mortem: scale-fold-into-B put 72 pk_muls on the MFMA B-operand
// critical path -> regression; chain-end fmacs are the right place, they just
// need to be deferred. Register worst case: 124 arch + 96 acc = 220 <= 256.

#define DSTATE 128
#define BATCH  16384
#define NSTEPS 7
#define BT     64
#define NSL    585          // slices per d-tile: 64*9 pair + 8 linear + 1 pad

typedef __attribute__((ext_vector_type(8)))  short  short8;   // 8 bf16 = 4 VGPRs
typedef __attribute__((ext_vector_type(16))) float  f32x16;   // MFMA 32x32 C/D

__device__ __forceinline__ unsigned short f2bf(float f){
    unsigned int u = __float_as_uint(f);
    u += 0x7fff + ((u >> 16) & 1);          // RNE
    return (unsigned short)(u >> 16);
}

// Pack symmetric-folded W into bf16 MFMA-A fragments, uniform-9 pair stream.
// Pair p at positions 9p..9p+8: first 8-(p>>4) slices are row p (j-blocks
// p>>4..7), remaining 1+(p>>4) are row 127-p (j-blocks 7-(p>>4)..7).
// Fragment layout: A[m][k], m=lane&31 -> d=32t+m, k=(lane>>5)*8+e -> j=16*s+k.
__global__ void prep_kernel(const float* __restrict__ W, short8* __restrict__ A){
    int gid = blockIdx.x * 256 + threadIdx.x;
    const int ntotal = 4 * 130 * 8 * 64;
    if (gid >= ntotal) return;
    int lane = gid & 63; int r = gid >> 6;
    int s = r & 7;  r >>= 3;
    int row = r % 130;
    int t   = r / 130;
    int d  = t * 32 + (lane & 31);
    int kb = (lane >> 5) * 8;
    int dst;
    bool zero = false;
    if (row < 64){
        int sl = row >> 4;
        if (s < sl) return;
        dst = t * NSL + 9 * row + (s - sl);
    } else if (row < 128){
        int p  = 127 - row;
        int sl = row >> 4;
        if (s < sl) return;
        int ca = 8 - (p >> 4);
        dst = t * NSL + 9 * p + ca + (s - sl);
    } else if (row == 128){
        dst = t * NSL + 576 + s;               // linear (W1) row
    } else {
        if (s) return;                         // zero pad slice
        dst = t * NSL + 584;
        zero = true;
    }
    union { short8 v; unsigned short u[8]; } fr;
#pragma unroll
    for (int e = 0; e < 8; ++e){
        int j = s * 16 + kb + e;
        float v;
        if (zero) v = 0.0f;
        else if (row < 128){
            if      (j < row)  v = 0.0f;
            else if (j == row) v = W[(129 + 128 * row + j) * 128 + d];
            else               v = W[(129 + 128 * row + j) * 128 + d]
                                 + W[(129 + 128 * j + row) * 128 + d];
        } else {
            v = W[(1 + j) * 128 + d];
        }
        fr.u[e] = f2bf(v);
    }
    A[(size_t)dst * 64 + lane] = fr.v;
}

__global__ __launch_bounds__(512)
void taylor_kernel(const float* __restrict__ X, const float* __restrict__ W,
                   const float* __restrict__ tini, const float* __restrict__ lini,
                   const short8* __restrict__ A, float* __restrict__ out)
{
    __shared__ float  x_lds[DSTATE * BT];      // fp32 master state [d][b], 32 KB
    __shared__ float  w0_lds[DSTATE];
    __shared__ short8 bpack[2 * 8 * 64];       // B frags, 2 groups x 8 slices, 16 KB
    __shared__ float  sc_lds[2][4 * 64 * 17];  // K-merge scratch, 34.8 KB

    const int tid  = threadIdx.x;
    const int lane = tid & 63;
    const int w    = tid >> 6;
    const int t    = w & 3;                    // d-tile
    const int g    = w >> 2;                   // K-half (pairs 0..31 / 32..63+lin)
    const int ln   = lane & 31;
    const int hi   = lane >> 5;
    const int b0   = blockIdx.x * BT;

    // ---- init x0 = [X | t_init | l_init] ----
#pragma unroll
    for (int it = 0; it < 16; ++it){
        int entry = tid + it * 512;            // entry = b*128 + d
        int b = entry >> 7, d = entry & 127;
        float v;
        if      (d < 120) v = X[(b0 + b) * 120 + d];
        else if (d < 124) v = tini[d - 120];
        else              v = lini[d - 124];
        x_lds[d * BT + b] = v;
    }
    if (tid < DSTATE) w0_lds[tid] = W[tid];

    // wave's half-stream base: g0 -> slice 0, g1 -> slice 288 (pair 32)
    const short8* const Aw = A + ((size_t)t * NSL + (size_t)g * 288) * 64 + lane;
    const f32x16 zero16 = {};

#pragma unroll 1
    for (int step = 0; step < NSTEPS; ++step){
        __syncthreads();                       // (A) x_lds stable

        // last-step pruning: only d-tile 3 contributes to out dims 120..123
        const bool active = (step < NSTEPS - 1) || (t == 3);

        const short8* ap = Aw;
        short8 abuf[9];
        if (active){
#pragma unroll
            for (int s = 0; s < 9; ++s) abuf[s] = ap[s * 64];
            ap += 9 * 64;
        }

        // ---- build bpack (1024 frags, 2 per thread) while loads fly ----
#pragma unroll
        for (int f0 = 0; f0 < 2; ++f0){
            int f  = tid + f0 * 512;
            int gg = f >> 9, s = (f >> 6) & 7, l = f & 63;
            int c  = gg * 32 + (l & 31);
            int jb = 16 * s + 8 * (l >> 5);
            union { short8 v; unsigned short u[8]; } fr;
#pragma unroll
            for (int e = 0; e < 8; ++e)
                fr.u[e] = f2bf(x_lds[(jb + e) * BT + c]);
            bpack[f] = fr.v;
        }

        // ---- acc: g0 carries x_old + W0 for both groups; g1 pure partial ----
        f32x16 acc0, acc1;
        if (active){
            if (g == 0){
#pragma unroll
                for (int r = 0; r < 16; ++r){
                    int d = 32 * t + (r & 3) + 8 * (r >> 2) + 4 * hi;
                    acc0[r] = x_lds[d * BT + ln]      + w0_lds[d];
                    acc1[r] = x_lds[d * BT + 32 + ln] + w0_lds[d];
                }
            } else {
#pragma unroll
                for (int r = 0; r < 16; ++r){ acc0[r] = 0.f; acc1[r] = 0.f; }
            }
        }

        __syncthreads();                       // (B) bpack visible

        if (active){
            short8 bfrag0[8], bfrag1[8];       // B reg-cache for current BK block
            f32x16 Yp0, Yp1;                   // carried Y transients (deferred)
            float  cs0a, cs0b;                 // carried Y scales

            // One pair: [deferred Y-fmacs of prev pair] -> Z chains -> Y chains
            // (into Yp) -> Z fmacs. abuf[s] reloaded for next pair right after
            // its consumers issue. Z completes during the Y-issue span; Y is
            // consumed one pair later -> no chain-end stall anywhere.
#define ZYCORE(BK)                                                              \
                f32x16 Z0, Z1;                                                  \
                _Pragma("unroll")                                               \
                for (int s = 0; s < 1 + (BK); ++s){                             \
                    Z0 = __builtin_amdgcn_mfma_f32_32x32x16_bf16(abuf[8 - (BK) + s], bfrag0[7 - 2 * (BK) + s], s ? Z0 : zero16, 0, 0, 0); \
                    Z1 = __builtin_amdgcn_mfma_f32_32x32x16_bf16(abuf[8 - (BK) + s], bfrag1[7 - 2 * (BK) + s], s ? Z1 : zero16, 0, 0, 0); \
                    abuf[8 - (BK) + s] = ap[(8 - (BK) + s) * 64];               \
                }                                                               \
                _Pragma("unroll")                                               \
                for (int s = 0; s < 8 - (BK); ++s){                             \
                    Yp0 = __builtin_amdgcn_mfma_f32_32x32x16_bf16(abuf[s], bfrag0[s], s ? Yp0 : zero16, 0, 0, 0); \
                    Yp1 = __builtin_amdgcn_mfma_f32_32x32x16_bf16(abuf[s], bfrag1[s], s ? Yp1 : zero16, 0, 0, 0); \
                    abuf[s] = ap[s * 64];                                       \
                }                                                               \
                ap += 9 * 64;

#define BLOAD(BK)                                                               \
            _Pragma("unroll")                                                   \
            for (int s = 0; s < 8 - (BK); ++s){                                 \
                bfrag0[s] = bpack[((BK) + s) * 64 + lane];                      \
                bfrag1[s] = bpack[512 + ((BK) + s) * 64 + lane];                \
            }

#define PROLOG(BK, P)                                                           \
            BLOAD(BK)                                                           \
            {                                                                   \
                cs0a = x_lds[(P) * BT + ln];                                    \
                cs0b = x_lds[(P) * BT + 32 + ln];                               \
                float s1a = x_lds[(127 - (P)) * BT + ln];                       \
                float s1b = x_lds[(127 - (P)) * BT + 32 + ln];                  \
                ZYCORE(BK)                                                      \
                acc0 += s1a * Z0;                                               \
                acc1 += s1b * Z1;                                               \
            }

#define PAIRS(BK, QA, QB)                                                       \
            BLOAD(BK)                                                           \
            _Pragma("unroll 2")                                                 \
            for (int q = (QA); q < (QB); ++q){                                  \
                const int p = 16 * (BK) + q;                                    \
                acc0 += cs0a * Yp0;            /* deferred: prev pair's Y */    \
                acc1 += cs0b * Yp1;                                             \
                cs0a = x_lds[p * BT + ln];                                      \
                cs0b = x_lds[p * BT + 32 + ln];                                 \
                float s1a = x_lds[(127 - p) * BT + ln];                         \
                float s1b = x_lds[(127 - p) * BT + 32 + ln];                    \
                ZYCORE(BK)                                                      \
                acc0 += s1a * Z0;                                               \
                acc1 += s1b * Z1;                                               \
            }

            if (g == 0){
                PROLOG(0, 0)
                PAIRS(0, 1, 16)
                PAIRS(1, 0, 16)
                acc0 += cs0a * Yp0;            // epilogue: last pair's Y
                acc1 += cs0b * Yp1;
                // trailing reloads read pair 32 (in-bounds, discarded)
            } else {
                PROLOG(2, 32)
                PAIRS(2, 1, 16)
                PAIRS(3, 0, 16)
                acc0 += cs0a * Yp0;
                acc1 += cs0b * Yp1;
                // linear (W1) row: scale==1 -> accumulate DIRECTLY into acc
                // via the MFMA C-operand (abuf holds slices 576..583 + pad)
                BLOAD(0)
#pragma unroll
                for (int s = 0; s < 8; ++s){
                    acc0 = __builtin_amdgcn_mfma_f32_32x32x16_bf16(abuf[s], bfrag0[s], acc0, 0, 0, 0);
                    acc1 = __builtin_amdgcn_mfma_f32_32x32x16_bf16(abuf[s], bfrag1[s], acc1, 0, 0, 0);
                }
                // publish K-half partials
#pragma unroll
                for (int r = 0; r < 16; ++r){
                    sc_lds[0][(t * 64 + lane) * 17 + r] = acc0[r];
                    sc_lds[1][(t * 64 + lane) * 17 + r] = acc1[r];
                }
            }
#undef PAIRS
#undef PROLOG
#undef BLOAD
#undef ZYCORE
        }

        __syncthreads();                       // (C) reads done + scratch visible
        if (active && g == 0){
#pragma unroll
            for (int r = 0; r < 16; ++r){
                acc0[r] += sc_lds[0][(t * 64 + lane) * 17 + r];
                acc1[r] += sc_lds[1][(t * 64 + lane) * 17 + r];
            }
            if (step < NSTEPS - 1){
#pragma unroll
                for (int r = 0; r < 16; ++r){
                    int d = 32 * t + (r & 3) + 8 * (r >> 2) + 4 * hi;
                    x_lds[d * BT + ln]      = acc0[r];
                    x_lds[d * BT + 32 + ln] = acc1[r];
                }
            } else {
                // out dims 120..123 -> tile 3, regs 12..15 @ hi==0
                if (hi == 0){
                    *(float4*)(out + (size_t)(b0 + ln) * 4) =
                        make_float4(acc0[12], acc0[13], acc0[14], acc0[15]);
                    *(float4*)(out + (size_t)(b0 + 32 + ln) * 4) =
                        make_float4(acc1[12], acc1[13], acc1[14], acc1[15]);
                }
            }
        }
        // next iteration's barrier (A) orders g0's x write vs g1's next reads
    }
}

extern "C" void kernel_launch(void* const* d_in, const int* in_sizes, int n_in,
                              void* d_out, int out_size, void* d_ws, size_t ws_size,
                              hipStream_t stream)
{
    const float* X  = (const float*)d_in[0];
    const float* W  = (const float*)d_in[1];
    const float* ti = (const float*)d_in[2];
    const float* li = (const float*)d_in[3];
    float* out      = (float*)d_out;
    short8* A       = (short8*)d_ws;           // 4*585*64*16 B = 2.40 MB

    const int ntotal = 4 * 130 * 8 * 64;
    prep_kernel<<<(ntotal + 255) / 256, 256, 0, stream>>>(W, A);
    taylor_kernel<<<BATCH / BT, 512, 0, stream>>>(X, W, ti, li, A, out);
}

// Round 12
// 307.649 us; speedup vs baseline: 1.1456x; 1.0818x over previous
//
#include <hip/hip_runtime.h>
#include <hip/hip_bf16.h>

// TaylorMap, symmetric-packed quadratic, uniform-9 pair stream (bf16).
// R12 = R9 core (immediate chain-end fmacs -- proven zero-spill, 271 us)
//     + step-7 pruning (only d-tile 3 computes in the last step)
//     + linear (W1) row accumulated directly into acc via MFMA C-operand.
// R10/R11 post-mortems: scale-fold-into-B (R10) put pk_muls on the MFMA
// critical path; deferred-Y (R11) carried +32 acc-class regs -> small scratch
// spill that ate the pruning win. Chain-end latency is NOT the binding stall;
// the residual gap at 2 waves/SIMD is A-operand L1-fill (~38k cyc/CU/step)
// co-equal with the MFMA pipe floor (~37.7k). Keep the compute shape fixed.

#define DSTATE 128
#define BATCH  16384
#define NSTEPS 7
#define BT     64
#define NSL    585          // slices per d-tile: 64*9 pair + 8 linear + 1 pad

typedef __attribute__((ext_vector_type(8)))  short  short8;   // 8 bf16 = 4 VGPRs
typedef __attribute__((ext_vector_type(16))) float  f32x16;   // MFMA 32x32 C/D

__device__ __forceinline__ unsigned short f2bf(float f){
    unsigned int u = __float_as_uint(f);
    u += 0x7fff + ((u >> 16) & 1);          // RNE
    return (unsigned short)(u >> 16);
}

// Pack symmetric-folded W into bf16 MFMA-A fragments, uniform-9 pair stream.
// Pair p at positions 9p..9p+8: first 8-(p>>4) slices are row p (j-blocks
// p>>4..7), remaining 1+(p>>4) are row 127-p (j-blocks 7-(p>>4)..7).
// Fragment layout: A[m][k], m=lane&31 -> d=32t+m, k=(lane>>5)*8+e -> j=16*s+k.
__global__ void prep_kernel(const float* __restrict__ W, short8* __restrict__ A){
    int gid = blockIdx.x * 256 + threadIdx.x;
    const int ntotal = 4 * 130 * 8 * 64;
    if (gid >= ntotal) return;
    int lane = gid & 63; int r = gid >> 6;
    int s = r & 7;  r >>= 3;
    int row = r % 130;
    int t   = r / 130;
    int d  = t * 32 + (lane & 31);
    int kb = (lane >> 5) * 8;
    int dst;
    bool zero = false;
    if (row < 64){
        int sl = row >> 4;
        if (s < sl) return;
        dst = t * NSL + 9 * row + (s - sl);
    } else if (row < 128){
        int p  = 127 - row;
        int sl = row >> 4;
        if (s < sl) return;
        int ca = 8 - (p >> 4);
        dst = t * NSL + 9 * p + ca + (s - sl);
    } else if (row == 128){
        dst = t * NSL + 576 + s;               // linear (W1) row
    } else {
        if (s) return;                         // zero pad slice
        dst = t * NSL + 584;
        zero = true;
    }
    union { short8 v; unsigned short u[8]; } fr;
#pragma unroll
    for (int e = 0; e < 8; ++e){
        int j = s * 16 + kb + e;
        float v;
        if (zero) v = 0.0f;
        else if (row < 128){
            if      (j < row)  v = 0.0f;
            else if (j == row) v = W[(129 + 128 * row + j) * 128 + d];
            else               v = W[(129 + 128 * row + j) * 128 + d]
                                 + W[(129 + 128 * j + row) * 128 + d];
        } else {
            v = W[(1 + j) * 128 + d];
        }
        fr.u[e] = f2bf(v);
    }
    A[(size_t)dst * 64 + lane] = fr.v;
}

__global__ __launch_bounds__(512)
void taylor_kernel(const float* __restrict__ X, const float* __restrict__ W,
                   const float* __restrict__ tini, const float* __restrict__ lini,
                   const short8* __restrict__ A, float* __restrict__ out)
{
    __shared__ float  x_lds[DSTATE * BT];      // fp32 master state [d][b], 32 KB
    __shared__ float  w0_lds[DSTATE];
    __shared__ short8 bpack[2 * 8 * 64];       // B frags, 2 groups x 8 slices, 16 KB
    __shared__ float  sc_lds[2][4 * 64 * 17];  // K-merge scratch, 34.8 KB

    const int tid  = threadIdx.x;
    const int lane = tid & 63;
    const int w    = tid >> 6;
    const int t    = w & 3;                    // d-tile
    const int g    = w >> 2;                   // K-half (pairs 0..31 / 32..63+lin)
    const int ln   = lane & 31;
    const int hi   = lane >> 5;
    const int b0   = blockIdx.x * BT;

    // ---- init x0 = [X | t_init | l_init] ----
#pragma unroll
    for (int it = 0; it < 16; ++it){
        int entry = tid + it * 512;            // entry = b*128 + d
        int b = entry >> 7, d = entry & 127;
        float v;
        if      (d < 120) v = X[(b0 + b) * 120 + d];
        else if (d < 124) v = tini[d - 120];
        else              v = lini[d - 124];
        x_lds[d * BT + b] = v;
    }
    if (tid < DSTATE) w0_lds[tid] = W[tid];

    // wave's half-stream base: g0 -> slice 0, g1 -> slice 288 (pair 32)
    const short8* const Aw = A + ((size_t)t * NSL + (size_t)g * 288) * 64 + lane;
    const f32x16 zero16 = {};

#pragma unroll 1
    for (int step = 0; step < NSTEPS; ++step){
        __syncthreads();                       // (A) x_lds stable

        // last-step pruning: only d-tile 3 feeds out dims 120..123
        const bool active = (step < NSTEPS - 1) || (t == 3);

        const short8* ap = Aw;
        short8 abuf[9];
        if (active){
#pragma unroll
            for (int s = 0; s < 9; ++s) abuf[s] = ap[s * 64];
            ap += 9 * 64;
        }

        // ---- build bpack (1024 frags, 2 per thread) while loads fly ----
#pragma unroll
        for (int f0 = 0; f0 < 2; ++f0){
            int f  = tid + f0 * 512;
            int gg = f >> 9, s = (f >> 6) & 7, l = f & 63;
            int c  = gg * 32 + (l & 31);
            int jb = 16 * s + 8 * (l >> 5);
            union { short8 v; unsigned short u[8]; } fr;
#pragma unroll
            for (int e = 0; e < 8; ++e)
                fr.u[e] = f2bf(x_lds[(jb + e) * BT + c]);
            bpack[f] = fr.v;
        }

        // ---- acc: g0 carries x_old + W0 for both groups; g1 pure partial ----
        f32x16 acc0, acc1;
        if (active){
            if (g == 0){
#pragma unroll
                for (int r = 0; r < 16; ++r){
                    int d = 32 * t + (r & 3) + 8 * (r >> 2) + 4 * hi;
                    acc0[r] = x_lds[d * BT + ln]      + w0_lds[d];
                    acc1[r] = x_lds[d * BT + 32 + ln] + w0_lds[d];
                }
            } else {
#pragma unroll
                for (int r = 0; r < 16; ++r){ acc0[r] = 0.f; acc1[r] = 0.f; }
            }
        }

        __syncthreads();                       // (B) bpack visible

        if (active){
            short8 bfrag0[8], bfrag1[8];       // B reg-cache for current BK block

            // R9 core: pair p=16*BK+q, rows (p,127-p). Y: slices BK..7
            // (abuf[0..7-BK]); Z: slices 7-BK..7 (abuf[8-BK..8], bfrag
            // 7-2BK+s). Immediate chain-end fmacs (proven zero-spill shape).
            // abuf[s] reloaded for the NEXT pair right after its consumers.
#define PAIRS(BK)                                                               \
            {                                                                   \
                _Pragma("unroll")                                               \
                for (int s = 0; s < 8 - (BK); ++s){                             \
                    bfrag0[s] = bpack[((BK) + s) * 64 + lane];                  \
                    bfrag1[s] = bpack[512 + ((BK) + s) * 64 + lane];            \
                }                                                               \
                _Pragma("unroll 2")                                             \
                for (int q = 0; q < 16; ++q){                                   \
                    const int p = 16 * (BK) + q;                                \
                    float s0a = x_lds[p * BT + ln];                             \
                    float s0b = x_lds[p * BT + 32 + ln];                        \
                    float s1a = x_lds[(127 - p) * BT + ln];                     \
                    float s1b = x_lds[(127 - p) * BT + 32 + ln];                \
                    f32x16 Y0, Y1;                                              \
                    _Pragma("unroll")                                           \
                    for (int s = 0; s < 8 - (BK); ++s){                         \
                        Y0 = __builtin_amdgcn_mfma_f32_32x32x16_bf16(abuf[s], bfrag0[s], s ? Y0 : zero16, 0, 0, 0); \
                        Y1 = __builtin_amdgcn_mfma_f32_32x32x16_bf16(abuf[s], bfrag1[s], s ? Y1 : zero16, 0, 0, 0); \
                        abuf[s] = ap[s * 64];                                   \
                    }                                                           \
                    acc0 += s0a * Y0;                                           \
                    acc1 += s0b * Y1;                                           \
                    f32x16 Z0, Z1;                                              \
                    _Pragma("unroll")                                           \
                    for (int s = 0; s < 1 + (BK); ++s){                         \
                        Z0 = __builtin_amdgcn_mfma_f32_32x32x16_bf16(abuf[8 - (BK) + s], bfrag0[7 - 2 * (BK) + s], s ? Z0 : zero16, 0, 0, 0); \
                        Z1 = __builtin_amdgcn_mfma_f32_32x32x16_bf16(abuf[8 - (BK) + s], bfrag1[7 - 2 * (BK) + s], s ? Z1 : zero16, 0, 0, 0); \
                        abuf[8 - (BK) + s] = ap[(8 - (BK) + s) * 64];           \
                    }                                                           \
                    acc0 += s1a * Z0;                                           \
                    acc1 += s1b * Z1;                                           \
                    ap += 9 * 64;                                               \
                }                                                               \
            }

            if (g == 0){
                PAIRS(0) PAIRS(1)
                // trailing reloads read pair 32 (in-bounds, discarded)
            } else {
                PAIRS(2) PAIRS(3)
                // linear (W1) row: scale==1 -> accumulate DIRECTLY into acc
                // via the MFMA C-operand (abuf holds slices 576..583 + pad)
#pragma unroll
                for (int s = 0; s < 8; ++s){
                    bfrag0[s] = bpack[s * 64 + lane];
                    bfrag1[s] = bpack[512 + s * 64 + lane];
                }
#pragma unroll
                for (int s = 0; s < 8; ++s){
                    acc0 = __builtin_amdgcn_mfma_f32_32x32x16_bf16(abuf[s], bfrag0[s], acc0, 0, 0, 0);
                    acc1 = __builtin_amdgcn_mfma_f32_32x32x16_bf16(abuf[s], bfrag1[s], acc1, 0, 0, 0);
                }
                // publish K-half partials
#pragma unroll
                for (int r = 0; r < 16; ++r){
                    sc_lds[0][(t * 64 + lane) * 17 + r] = acc0[r];
                    sc_lds[1][(t * 64 + lane) * 17 + r] = acc1[r];
                }
            }
#undef PAIRS
        }

        __syncthreads();                       // (C) reads done + scratch visible
        if (active && g == 0){
#pragma unroll
            for (int r = 0; r < 16; ++r){
                acc0[r] += sc_lds[0][(t * 64 + lane) * 17 + r];
                acc1[r] += sc_lds[1][(t * 64 + lane) * 17 + r];
            }
            if (step < NSTEPS - 1){
#pragma unroll
                for (int r = 0; r < 16; ++r){
                    int d = 32 * t + (r & 3) + 8 * (r >> 2) + 4 * hi;
                    x_lds[d * BT + ln]      = acc0[r];
                    x_lds[d * BT + 32 + ln] = acc1[r];
                }
            } else if (hi == 0){
                // out dims 120..123 -> tile 3, regs 12..15 @ hi==0
                *(float4*)(out + (size_t)(b0 + ln) * 4) =
                    make_float4(acc0[12], acc0[13], acc0[14], acc0[15]);
                *(float4*)(out + (size_t)(b0 + 32 + ln) * 4) =
                    make_float4(acc1[12], acc1[13], acc1[14], acc1[15]);
            }
        }
        // next iteration's barrier (A) orders g0's x write vs g1's next reads
    }
}

extern "C" void kernel_launch(void* const* d_in, const int* in_sizes, int n_in,
                              void* d_out, int out_size, void* d_ws, size_t ws_size,
                              hipStream_t stream)
{
    const float* X  = (const float*)d_in[0];
    const float* W  = (const float*)d_in[1];
    const float* ti = (const float*)d_in[2];
    const float* li = (const float*)d_in[3];
    float* out      = (float*)d_out;
    short8* A       = (short8*)d_ws;           // 4*585*64*16 B = 2.40 MB

    const int ntotal = 4 * 130 * 8 * 64;
    prep_kernel<<<(ntotal + 255) / 256, 256, 0, stream>>>(W, A);
    taylor_kernel<<<BATCH / BT, 512, 0, stream>>>(X, W, ti, li, A, out);
}